// Round 1
// 485.991 us; speedup vs baseline: 1.1613x; 1.1613x over previous
//
#include <hip/hip_runtime.h>
#include <cstdint>
#include <cstddef>

// Problem constants: P=2048, K=8, T=32, C=16384, F=128
#define PP 2048
#define KK 8
#define TT 32
#define FF 128
#define MB 8
#define NBLK (PP/MB)
#define NTHR 512
#define NSTEP (KK*TT)

typedef __attribute__((ext_vector_type(8))) short short8;  // 8 bf16 (4 VGPRs)
typedef __attribute__((ext_vector_type(4))) float f32x4;   // MFMA C/D frag

__device__ __forceinline__ uint32_t fbits(float x){ union{float f;uint32_t u;}c;c.f=x;return c.u; }
// f32 -> bf16 bits, round-to-nearest-even (3-4 VALU ops)
__device__ __forceinline__ uint32_t rne16(uint32_t u){
    return (u + 0x7fffu + ((u >> 16) & 1u)) >> 16;
}
__device__ __forceinline__ short bf_rne(float x){ return (short)rne16(fbits(x)); }
__device__ __forceinline__ uint32_t pk_rne(float a, float b){
    return rne16(fbits(a)) | (rne16(fbits(b)) << 16);
}
__device__ __forceinline__ float sigm(float x){
    float t = __expf(-x);                    // x->-inf: t=inf -> rcp=0; x->inf: t=0 -> 1
    return __builtin_amdgcn_rcpf(1.f + t);
}
__device__ __forceinline__ float tanh_fast(float x){
    float e = __expf(-2.f * x);              // saturates correctly via inf -> rcp -> 0
    return __builtin_amdgcn_rcpf(1.f + e) * 2.f - 1.f;
}

// Block: 8 paths x 256 GRU steps; 256 blocks -> all 256 CUs (was 128).
// 8 waves; wave w owns gate columns f in [16w,16w+16) (tiles {w,w+8,w+16}).
// A-frags carry 8 paths duplicated into rows 8-15 with a SHUFFLED dup map
// (rows 8-15 = paths {2,3,0,1,6,7,4,5}) so every lane's C regs {0,1} are a
// distinct valid (path,col) pair: all 64 lanes do gate math for 2 rows with
// STATIC vector indices. Duplication is consumer-side only: LDS holds 8 rows
// (32 slots/chunk); dup-row lanes read the same address (free broadcast).
// r/z gates: x- and h-MFMAs chain into one accumulator (r=sigm(xr+hr)),
// removing the separate vec-adds; n gate stays split (needs xn + r*hn).
// Sigma-swizzled h layout (slot = (p>>2) + 2*((p&3)^qq) + 8*qq): producer
// b16 scatter <=2-way (free), consumer ds_read_b128 conflict-free.
// x staged pre-converted (RNE) by waves 0-3 only, one-step-ahead global
// prefetch. One barrier per step.
__global__ __launch_bounds__(NTHR, 2) void gru_mfma4(
    const float* __restrict__ h0,    // [P, F]
    const float* __restrict__ feat,  // [C, T, F]
    const float* __restrict__ w_ih,  // [3F, F]
    const float* __restrict__ w_hh,  // [3F, F]
    const float* __restrict__ b_ih,  // [3F]
    const float* __restrict__ b_hh,  // [3F]
    const int* __restrict__ idx,     // [P, K]
    float* __restrict__ out)         // [P, F]
{
    const int tid  = threadIdx.x;
    const int w    = tid >> 6;
    const int lane = tid & 63;
    const int q    = lane >> 4;
    const int nl   = lane & 15;
    const int p0   = blockIdx.x * MB;

    __shared__ __align__(16) short xfr[2][4][32][8];  // x frags, 8 rows (identity slots)
    __shared__ __align__(16) short hhi[2][4][32][8];  // h frags, 8 rows (sigma slots)
    __shared__ int cix[MB][KK];

    // ---- B-fragments (weights, RNE bf16) resident in VGPRs.
    short8 wbi[3][4], wbh[3][4];
#pragma unroll
    for (int tt = 0; tt < 3; ++tt) {
        const int g = (w + 8 * tt) * 16 + nl;
#pragma unroll
        for (int c = 0; c < 4; ++c) {
            const float* wi = w_ih + (size_t)g * FF + c * 32 + q * 8;
            const float* wh = w_hh + (size_t)g * FF + c * 32 + q * 8;
            short8 a, b;
#pragma unroll
            for (int j = 0; j < 8; ++j) { a[j] = bf_rne(wi[j]); b[j] = bf_rne(wh[j]); }
            wbi[tt][c] = a; wbh[tt][c] = b;
        }
    }
    const int fcol = w * 16 + nl;
    const float bR  = b_ih[fcol] + b_hh[fcol];
    const float bZ  = b_ih[FF + fcol] + b_hh[FF + fcol];
    const float bNi = b_ih[2 * FF + fcol];
    const float bNh = b_hh[2 * FF + fcol];

    if (tid < MB * KK) cix[tid >> 3][tid & 7] = idx[(p0 + (tid >> 3)) * KK + (tid & 7)];
    __syncthreads();  // cix ready for stagers

    // ---- producer-side constants: lane owns paths {pb, pb+1} at column fcol
    const int qqF = 2 * (w & 1) + (nl >> 3);
    const int jF  = nl & 7;
    const int cF  = w >> 1;
    const int pb  = 4 * (q & 1) + 2 * (q >> 1);   // q=0->{0,1} 1->{4,5} 2->{2,3} 3->{6,7}
    int sp[2];
#pragma unroll
    for (int j = 0; j < 2; ++j) {
        const int p = pb + j;
        sp[j] = (p >> 2) + 2 * ((p & 3) ^ qqF) + 8 * qqF;
    }

    // ---- consumer-side constants: A-frag row -> path (shuffled dup for rows 8-15)
    const int row = lane & 15;
    const int pr  = (row < 8) ? row : ((row & 4) | ((row & 3) ^ 2));
    const int xslot = pr + 8 * q;                               // identity layout
    const int hslot = (pr >> 2) + 2 * ((pr & 3) ^ q) + 8 * q;   // sigma layout

    // ---- h0: f32 master in regs + RNE bf16 frags into buf0
    float hm[2];
#pragma unroll
    for (int j = 0; j < 2; ++j) {
        const float h = h0[(size_t)(p0 + pb + j) * FF + fcol];
        hm[j] = h;
        hhi[0][cF][sp[j]][jF] = bf_rne(h);
    }

    // ---- x stager mapping: waves 0-3 only; thread = half a frag row
    const bool stg    = tid < 256;
    const int  c_s    = tid >> 6;          // chunk (0..3 for stagers)
    const int  r6     = tid & 63;
    const int  slot_s = r6 >> 1;           // 0..31: path + 8*qq
    const int  half   = r6 & 1;
    const int  path_s = slot_s & 7;
    const int  qq_s   = slot_s >> 3;
    const int  k0s    = c_s * 32 + qq_s * 8 + 4 * half;

    float4 xp;
    if (stg) {
        const int ch = cix[path_s][0];
        const float4 v = *(const float4*)(feat + (size_t)ch * (TT * FF) + k0s);
        uint2 pkd = { pk_rne(v.x, v.y), pk_rne(v.z, v.w) };
        *(uint2*)&xfr[0][c_s][slot_s][4 * half] = pkd;
        // prefetch x_1
        xp = *(const float4*)(feat + (size_t)ch * (TT * FF) + FF + k0s);
    }
    __syncthreads();

    int curb = 0;
    for (int s = 0; s < NSTEP; ++s) {
        const int nxtb = curb ^ 1;

        if (stg) {
            // stage x_{s+1} (loaded last iter) into next buffer
            if (s < NSTEP - 1) {
                uint2 pkd = { pk_rne(xp.x, xp.y), pk_rne(xp.z, xp.w) };
                *(uint2*)&xfr[nxtb][c_s][slot_s][4 * half] = pkd;
            }
            // prefetch x_{s+2} (fully latency-hidden behind this step)
            if (s < NSTEP - 2) {
                const int u = s + 2;
                const int ch = cix[path_s][u >> 5];
                xp = *(const float4*)(feat + (size_t)ch * (TT * FF) + (u & 31) * FF + k0s);
            }
        }

        // A-frags (all reads conflict-free b128, dup rows broadcast): 8 per lane
        short8 xa[4], ha[4];
#pragma unroll
        for (int c = 0; c < 4; ++c) {
            xa[c] = *(const short8*)&xfr[curb][c][xslot][0];
            ha[c] = *(const short8*)&hhi[curb][c][hslot][0];
        }

        f32x4 gR, gZ, axN, ahN;
        {   // r gate: x+h fused in one accumulator pair
            f32x4 a0 = {0.f,0.f,0.f,0.f}, a1 = {0.f,0.f,0.f,0.f};
            a0 = __builtin_amdgcn_mfma_f32_16x16x32_bf16(xa[0], wbi[0][0], a0, 0, 0, 0);
            a0 = __builtin_amdgcn_mfma_f32_16x16x32_bf16(xa[1], wbi[0][1], a0, 0, 0, 0);
            a1 = __builtin_amdgcn_mfma_f32_16x16x32_bf16(xa[2], wbi[0][2], a1, 0, 0, 0);
            a1 = __builtin_amdgcn_mfma_f32_16x16x32_bf16(xa[3], wbi[0][3], a1, 0, 0, 0);
            a0 = __builtin_amdgcn_mfma_f32_16x16x32_bf16(ha[0], wbh[0][0], a0, 0, 0, 0);
            a0 = __builtin_amdgcn_mfma_f32_16x16x32_bf16(ha[1], wbh[0][1], a0, 0, 0, 0);
            a1 = __builtin_amdgcn_mfma_f32_16x16x32_bf16(ha[2], wbh[0][2], a1, 0, 0, 0);
            a1 = __builtin_amdgcn_mfma_f32_16x16x32_bf16(ha[3], wbh[0][3], a1, 0, 0, 0);
            gR = a0 + a1;
        }
        {   // z gate: x+h fused
            f32x4 a0 = {0.f,0.f,0.f,0.f}, a1 = {0.f,0.f,0.f,0.f};
            a0 = __builtin_amdgcn_mfma_f32_16x16x32_bf16(xa[0], wbi[1][0], a0, 0, 0, 0);
            a0 = __builtin_amdgcn_mfma_f32_16x16x32_bf16(xa[1], wbi[1][1], a0, 0, 0, 0);
            a1 = __builtin_amdgcn_mfma_f32_16x16x32_bf16(xa[2], wbi[1][2], a1, 0, 0, 0);
            a1 = __builtin_amdgcn_mfma_f32_16x16x32_bf16(xa[3], wbi[1][3], a1, 0, 0, 0);
            a0 = __builtin_amdgcn_mfma_f32_16x16x32_bf16(ha[0], wbh[1][0], a0, 0, 0, 0);
            a0 = __builtin_amdgcn_mfma_f32_16x16x32_bf16(ha[1], wbh[1][1], a0, 0, 0, 0);
            a1 = __builtin_amdgcn_mfma_f32_16x16x32_bf16(ha[2], wbh[1][2], a1, 0, 0, 0);
            a1 = __builtin_amdgcn_mfma_f32_16x16x32_bf16(ha[3], wbh[1][3], a1, 0, 0, 0);
            gZ = a0 + a1;
        }
        {   // n gate: x and h kept separate (np = xn + r*hn)
            f32x4 a0 = {0.f,0.f,0.f,0.f}, a1 = {0.f,0.f,0.f,0.f};
            f32x4 u0 = {0.f,0.f,0.f,0.f}, u1 = {0.f,0.f,0.f,0.f};
            a0 = __builtin_amdgcn_mfma_f32_16x16x32_bf16(xa[0], wbi[2][0], a0, 0, 0, 0);
            a0 = __builtin_amdgcn_mfma_f32_16x16x32_bf16(xa[1], wbi[2][1], a0, 0, 0, 0);
            a1 = __builtin_amdgcn_mfma_f32_16x16x32_bf16(xa[2], wbi[2][2], a1, 0, 0, 0);
            a1 = __builtin_amdgcn_mfma_f32_16x16x32_bf16(xa[3], wbi[2][3], a1, 0, 0, 0);
            u0 = __builtin_amdgcn_mfma_f32_16x16x32_bf16(ha[0], wbh[2][0], u0, 0, 0, 0);
            u0 = __builtin_amdgcn_mfma_f32_16x16x32_bf16(ha[1], wbh[2][1], u0, 0, 0, 0);
            u1 = __builtin_amdgcn_mfma_f32_16x16x32_bf16(ha[2], wbh[2][2], u1, 0, 0, 0);
            u1 = __builtin_amdgcn_mfma_f32_16x16x32_bf16(ha[3], wbh[2][3], u1, 0, 0, 0);
            axN = a0 + a1; ahN = u0 + u1;
        }

        // gates + state update; lane owns 2 rows (C regs 0,1), static indices
#pragma unroll
        for (int j = 0; j < 2; ++j) {
            const float rg  = sigm(gR[j] + bR);
            const float zg  = sigm(gZ[j] + bZ);
            const float np_ = axN[j] + bNi + rg * (ahN[j] + bNh);
            const float ng  = tanh_fast(np_);
            const float h   = ng + zg * (hm[j] - ng);
            hm[j] = h;
            hhi[nxtb][cF][sp[j]][jF] = bf_rne(h);
        }
        __syncthreads();
        curb = nxtb;
    }

    // final h straight from registers
#pragma unroll
    for (int j = 0; j < 2; ++j)
        out[(size_t)(p0 + pb + j) * FF + fcol] = hm[j];
}

extern "C" void kernel_launch(void* const* d_in, const int* in_sizes, int n_in,
                              void* d_out, int out_size, void* d_ws, size_t ws_size,
                              hipStream_t stream) {
    const float* h0   = (const float*)d_in[0];
    const float* feat = (const float*)d_in[1];
    const float* wih  = (const float*)d_in[2];
    const float* whh  = (const float*)d_in[3];
    const float* bih  = (const float*)d_in[4];
    const float* bhh  = (const float*)d_in[5];
    const int*   idx  = (const int*)d_in[6];
    float*       out  = (float*)d_out;

    gru_mfma4<<<dim3(NBLK), dim3(NTHR), 0, stream>>>(
        h0, feat, wih, whh, bih, bhh, idx, out);
}

// Round 2
// 480.010 us; speedup vs baseline: 1.1758x; 1.0125x over previous
//
#include <hip/hip_runtime.h>
#include <cstdint>
#include <cstddef>

// Problem constants: P=2048, K=8, T=32, C=16384, F=128
#define PP 2048
#define KK 8
#define TT 32
#define FF 128
#define MB 8
#define NBLK (PP/MB)
#define NTHR 512
#define NSTEP (KK*TT)

typedef __attribute__((ext_vector_type(8))) short short8;  // 8 bf16 (4 VGPRs)
typedef __attribute__((ext_vector_type(4))) float f32x4;   // MFMA C/D frag

__device__ __forceinline__ uint32_t fbits(float x){ union{float f;uint32_t u;}c;c.f=x;return c.u; }
// f32 -> bf16 bits, round-to-nearest-even (3-4 VALU ops)
__device__ __forceinline__ uint32_t rne16(uint32_t u){
    return (u + 0x7fffu + ((u >> 16) & 1u)) >> 16;
}
__device__ __forceinline__ short bf_rne(float x){ return (short)rne16(fbits(x)); }
__device__ __forceinline__ uint32_t pk_rne(float a, float b){
    return rne16(fbits(a)) | (rne16(fbits(b)) << 16);
}
__device__ __forceinline__ float sigm(float x){
    float t = __expf(-x);                    // x->-inf: t=inf -> rcp=0; x->inf: t=0 -> 1
    return __builtin_amdgcn_rcpf(1.f + t);
}
__device__ __forceinline__ float tanh_fast(float x){
    float e = __expf(-2.f * x);              // saturates correctly via inf -> rcp -> 0
    return __builtin_amdgcn_rcpf(1.f + e) * 2.f - 1.f;
}

// Block: 8 paths x 256 GRU steps; 256 blocks -> all 256 CUs. 8 waves; wave w
// owns gate columns f in [16w,16w+16) (tiles {w,w+8,w+16}). A-frags carry the
// 8 paths duplicated into rows 8-15 (shuffled: rows 8-15 = paths
// {2,3,0,1,6,7,4,5}) so every lane's C regs {0,1} are a distinct (path,col)
// pair -> all 64 lanes do gate math for 2 rows with static indices.
// Duplication is consumer-side via LDS same-address broadcast.
//
// SOFTWARE PIPELINE (this version): the 12 x-projection MFMAs for step s+1
// run during step s, accumulating into persistent pax{R,Z,N} registers
// (init = bias broadcast, so all per-row bias adds vanish). The in-step
// critical path is only: barrier -> ds_read h-frags -> 4-deep h-MFMA chain
// (chained onto pax) -> gate VALU -> h write -> barrier. Stagers therefore
// write x_{s+2} during step s (consumers read x_{s+1} from the other buffer).
// Sigma-swizzled h layout (slot = (p>>2) + 2*((p&3)^qq) + 8*qq): producer
// b16 scatter <=2-way (free), consumer ds_read_b128 conflict-free.
// One barrier per step.
__global__ __launch_bounds__(NTHR, 2) void gru_mfma5(
    const float* __restrict__ h0,    // [P, F]
    const float* __restrict__ feat,  // [C, T, F]
    const float* __restrict__ w_ih,  // [3F, F]
    const float* __restrict__ w_hh,  // [3F, F]
    const float* __restrict__ b_ih,  // [3F]
    const float* __restrict__ b_hh,  // [3F]
    const int* __restrict__ idx,     // [P, K]
    float* __restrict__ out)         // [P, F]
{
    const int tid  = threadIdx.x;
    const int w    = tid >> 6;
    const int lane = tid & 63;
    const int q    = lane >> 4;
    const int nl   = lane & 15;
    const int p0   = blockIdx.x * MB;

    __shared__ __align__(16) short xfr[2][4][32][8];  // x frags, 8 rows (identity slots)
    __shared__ __align__(16) short hhi[2][4][32][8];  // h frags, 8 rows (sigma slots)
    __shared__ int cix[MB][KK];

    // ---- B-fragments (weights, RNE bf16) resident in VGPRs.
    short8 wbi[3][4], wbh[3][4];
#pragma unroll
    for (int tt = 0; tt < 3; ++tt) {
        const int g = (w + 8 * tt) * 16 + nl;
#pragma unroll
        for (int c = 0; c < 4; ++c) {
            const float* wi = w_ih + (size_t)g * FF + c * 32 + q * 8;
            const float* wh = w_hh + (size_t)g * FF + c * 32 + q * 8;
            short8 a, b;
#pragma unroll
            for (int j = 0; j < 8; ++j) { a[j] = bf_rne(wi[j]); b[j] = bf_rne(wh[j]); }
            wbi[tt][c] = a; wbh[tt][c] = b;
        }
    }
    const int fcol = w * 16 + nl;
    const float bR  = b_ih[fcol] + b_hh[fcol];
    const float bZ  = b_ih[FF + fcol] + b_hh[FF + fcol];
    const float bNi = b_ih[2 * FF + fcol];
    const float bNh = b_hh[2 * FF + fcol];

    if (tid < MB * KK) cix[tid >> 3][tid & 7] = idx[(p0 + (tid >> 3)) * KK + (tid & 7)];

    // ---- producer-side constants: lane owns paths {pb, pb+1} at column fcol
    const int qqF = 2 * (w & 1) + (nl >> 3);
    const int jF  = nl & 7;
    const int cF  = w >> 1;
    const int pb  = 4 * (q & 1) + 2 * (q >> 1);   // q=0->{0,1} 1->{4,5} 2->{2,3} 3->{6,7}
    int sp[2];
#pragma unroll
    for (int j = 0; j < 2; ++j) {
        const int p = pb + j;
        sp[j] = (p >> 2) + 2 * ((p & 3) ^ qqF) + 8 * qqF;
    }

    // ---- consumer-side constants: A-frag row -> path (shuffled dup for rows 8-15)
    const int row = lane & 15;
    const int pr  = (row < 8) ? row : ((row & 4) | ((row & 3) ^ 2));
    const int xslot = pr + 8 * q;                               // identity layout
    const int hslot = (pr >> 2) + 2 * ((pr & 3) ^ q) + 8 * q;   // sigma layout

    // ---- h0: f32 master in regs + RNE bf16 frags into buf0
    float hm[2];
#pragma unroll
    for (int j = 0; j < 2; ++j) {
        const float h = h0[(size_t)(p0 + pb + j) * FF + fcol];
        hm[j] = h;
        hhi[0][cF][sp[j]][jF] = bf_rne(h);
    }

    // ---- x stager mapping: waves 0-3 only; thread = half a frag row
    const bool stg    = tid < 256;
    const int  c_s    = tid >> 6;          // chunk (0..3 for stagers)
    const int  r6     = tid & 63;
    const int  slot_s = r6 >> 1;           // 0..31: path + 8*qq
    const int  half   = r6 & 1;
    const int  path_s = slot_s & 7;
    const int  qq_s   = slot_s >> 3;
    const int  k0s    = c_s * 32 + qq_s * 8 + 4 * half;

    __syncthreads();  // B0: cix ready for stagers

    // prologue staging: x_0 -> xfr[0], x_1 -> xfr[1], prefetch x_2
    float4 xp;
    if (stg) {
        const int ch = cix[path_s][0];
        const float* base = feat + (size_t)ch * (TT * FF) + k0s;
        const float4 v0 = *(const float4*)(base);
        const float4 v1 = *(const float4*)(base + FF);
        uint2 p0d = { pk_rne(v0.x, v0.y), pk_rne(v0.z, v0.w) };
        uint2 p1d = { pk_rne(v1.x, v1.y), pk_rne(v1.z, v1.w) };
        *(uint2*)&xfr[0][c_s][slot_s][4 * half] = p0d;
        *(uint2*)&xfr[1][c_s][slot_s][4 * half] = p1d;
        xp = *(const float4*)(base + 2 * FF);
    }
    __syncthreads();  // B1: xfr[0], xfr[1], hhi[0] ready

    // prologue: x-accumulators for step 0 from x_0 (bias-folded init)
    f32x4 paxR, paxZ, paxN;
    {
        short8 xa0[4];
#pragma unroll
        for (int c = 0; c < 4; ++c) xa0[c] = *(const short8*)&xfr[0][c][xslot][0];
        __syncthreads();  // B2: xa0 reads done; step 0 stagers may overwrite xfr[0]

        f32x4 r = {bR, bR, bR, bR}, z = {bZ, bZ, bZ, bZ}, n = {bNi, bNi, bNi, bNi};
#pragma unroll
        for (int c = 0; c < 4; ++c) {
            r = __builtin_amdgcn_mfma_f32_16x16x32_bf16(xa0[c], wbi[0][c], r, 0, 0, 0);
            z = __builtin_amdgcn_mfma_f32_16x16x32_bf16(xa0[c], wbi[1][c], z, 0, 0, 0);
            n = __builtin_amdgcn_mfma_f32_16x16x32_bf16(xa0[c], wbi[2][c], n, 0, 0, 0);
        }
        paxR = r; paxZ = z; paxN = n;
    }

    int curb = 0;
    for (int s = 0; s < NSTEP; ++s) {
        const int nxtb = curb ^ 1;

        if (stg) {
            // stage x_{s+2} (loaded last iter) into the buffer consumers just freed
            if (s < NSTEP - 2) {
                uint2 pkd = { pk_rne(xp.x, xp.y), pk_rne(xp.z, xp.w) };
                *(uint2*)&xfr[curb][c_s][slot_s][4 * half] = pkd;
            }
            // prefetch x_{s+3} (fully latency-hidden behind this step)
            if (s < NSTEP - 3) {
                const int u = s + 3;
                const int ch = cix[path_s][u >> 5];
                xp = *(const float4*)(feat + (size_t)ch * (TT * FF) + (u & 31) * FF + k0s);
            }
        }

        // h-frags for this step (critical path), x-frags for next step
        short8 ha[4];
#pragma unroll
        for (int c = 0; c < 4; ++c) ha[c] = *(const short8*)&hhi[curb][c][hslot][0];
        short8 xn[4];
        if (s < NSTEP - 1) {
#pragma unroll
            for (int c = 0; c < 4; ++c) xn[c] = *(const short8*)&xfr[nxtb][c][xslot][0];
        }

        // h-MFMAs chained onto the saved x-accumulators (r,z) / fresh bNh acc (n)
        f32x4 ahN = {bNh, bNh, bNh, bNh};
#pragma unroll
        for (int c = 0; c < 4; ++c) {
            paxR = __builtin_amdgcn_mfma_f32_16x16x32_bf16(ha[c], wbh[0][c], paxR, 0, 0, 0);
            paxZ = __builtin_amdgcn_mfma_f32_16x16x32_bf16(ha[c], wbh[1][c], paxZ, 0, 0, 0);
            ahN  = __builtin_amdgcn_mfma_f32_16x16x32_bf16(ha[c], wbh[2][c], ahN, 0, 0, 0);
        }

        // gates + state update; lane owns 2 rows (C regs 0,1), static indices
#pragma unroll
        for (int j = 0; j < 2; ++j) {
            const float rg  = sigm(paxR[j]);
            const float zg  = sigm(paxZ[j]);
            const float np_ = paxN[j] + rg * ahN[j];
            const float ng  = tanh_fast(np_);
            const float h   = ng + zg * (hm[j] - ng);
            hm[j] = h;
            hhi[nxtb][cF][sp[j]][jF] = bf_rne(h);
        }

        // x-projection MFMAs for step s+1 (independent; drain through barrier)
        if (s < NSTEP - 1) {
            f32x4 r = {bR, bR, bR, bR}, z = {bZ, bZ, bZ, bZ}, n = {bNi, bNi, bNi, bNi};
#pragma unroll
            for (int c = 0; c < 4; ++c) {
                r = __builtin_amdgcn_mfma_f32_16x16x32_bf16(xn[c], wbi[0][c], r, 0, 0, 0);
                z = __builtin_amdgcn_mfma_f32_16x16x32_bf16(xn[c], wbi[1][c], z, 0, 0, 0);
                n = __builtin_amdgcn_mfma_f32_16x16x32_bf16(xn[c], wbi[2][c], n, 0, 0, 0);
            }
            paxR = r; paxZ = z; paxN = n;
        }

        __syncthreads();
        curb = nxtb;
    }

    // final h straight from registers
#pragma unroll
    for (int j = 0; j < 2; ++j)
        out[(size_t)(p0 + pb + j) * FF + fcol] = hm[j];
}

extern "C" void kernel_launch(void* const* d_in, const int* in_sizes, int n_in,
                              void* d_out, int out_size, void* d_ws, size_t ws_size,
                              hipStream_t stream) {
    const float* h0   = (const float*)d_in[0];
    const float* feat = (const float*)d_in[1];
    const float* wih  = (const float*)d_in[2];
    const float* whh  = (const float*)d_in[3];
    const float* bih  = (const float*)d_in[4];
    const float* bhh  = (const float*)d_in[5];
    const int*   idx  = (const int*)d_in[6];
    float*       out  = (float*)d_out;

    gru_mfma5<<<dim3(NBLK), dim3(NTHR), 0, stream>>>(
        h0, feat, wih, whh, bih, bhh, idx, out);
}

// Round 3
// 448.190 us; speedup vs baseline: 1.2593x; 1.0710x over previous
//
#include <hip/hip_runtime.h>
#include <cstdint>
#include <cstddef>

// Problem constants: P=2048, K=8, T=32, C=16384, F=128
#define PP 2048
#define KK 8
#define TT 32
#define FF 128
#define MB 8
#define NBLK (PP/MB)
#define NTHR 512
#define NSTEP (KK*TT)
#define NMAC (NSTEP/2)

typedef __attribute__((ext_vector_type(8))) short short8;  // 8 bf16 (4 VGPRs)
typedef __attribute__((ext_vector_type(4))) float f32x4;   // MFMA C/D frag

__device__ __forceinline__ uint32_t fbits(float x){ union{float f;uint32_t u;}c;c.f=x;return c.u; }
__device__ __forceinline__ uint32_t rne16(uint32_t u){
    return (u + 0x7fffu + ((u >> 16) & 1u)) >> 16;
}
__device__ __forceinline__ short bf_rne(float x){ return (short)rne16(fbits(x)); }
// HW packed f32->bf16 RNE: 1 instr replaces ~8 VALU ops (gfx950, no builtin)
__device__ __forceinline__ uint32_t cvtpk(float a, float b){
    uint32_t r;
    asm("v_cvt_pk_bf16_f32 %0, %1, %2" : "=v"(r) : "v"(a), "v"(b));
    return r;
}
__device__ __forceinline__ float sigm(float x){
    float t = __expf(-x);                    // x->-inf: t=inf -> rcp=0; x->inf: t=0 -> 1
    return __builtin_amdgcn_rcpf(1.f + t);
}
__device__ __forceinline__ float tanh_fast(float x){
    float e = __expf(-2.f * x);              // saturates correctly via inf -> rcp -> 0
    return __builtin_amdgcn_rcpf(1.f + e) * 2.f - 1.f;
}

// Block: 8 paths x 256 GRU steps; 256 blocks -> all 256 CUs. 8 waves; wave w
// owns gate columns f in [16w,16w+16) (tiles {w,w+8,w+16}). h A-frags carry
// the 8 paths duplicated into rows 8-15 (rows 8-15 = paths {2,3,0,1,6,7,4,5})
// so every lane's C regs {0,1} are a distinct (path,col) pair.
//
// DENSE-X (this version): x-projections for steps s+1 (rows 0-7, identity)
// and s+2 (rows 8-15, dup-shuffle map) are packed into ONE 16-row MFMA set
// per 2 steps -> x-MFMA issue halves (total matrix issue -25%). Consumer
// addressing is unchanged (same xslot); each lane picks the ring buffer by
// row<8. Post-MFMA, C regs {2,3} are exchanged lane<->lane+32 (6 shfl_xor +
// selects per macro) so every lane holds its own 2-value x-gates for both
// steps (verified per-reg: q<2 keep regs{0,1}=step s+1, receive s+2; q>=2
// reverse). Macro-iteration = 2 steps, 4-deep x ring (stagers write s+3,s+4;
// dense MFMA reads s+1,s+2), h buffers statically indexed by parity.
// Conversions use v_cvt_pk_bf16_f32 (1 instr vs ~8 VALU). 1 barrier/step.
__global__ __launch_bounds__(NTHR, 2) void gru_mfma6(
    const float* __restrict__ h0,    // [P, F]
    const float* __restrict__ feat,  // [C, T, F]
    const float* __restrict__ w_ih,  // [3F, F]
    const float* __restrict__ w_hh,  // [3F, F]
    const float* __restrict__ b_ih,  // [3F]
    const float* __restrict__ b_hh,  // [3F]
    const int* __restrict__ idx,     // [P, K]
    float* __restrict__ out)         // [P, F]
{
    const int tid  = threadIdx.x;
    const int w    = tid >> 6;
    const int lane = tid & 63;
    const int q    = lane >> 4;
    const int nl   = lane & 15;
    const int p0   = blockIdx.x * MB;

    __shared__ __align__(16) short xfr[4][4][32][8];  // x frag ring, 4 steps (8KB)
    __shared__ __align__(16) short hhi[2][4][32][8];  // h frags by parity (4KB)
    __shared__ int cix[MB][KK];

    // ---- B-fragments (weights, RNE bf16) resident in VGPRs.
    short8 wbi[3][4], wbh[3][4];
#pragma unroll
    for (int tt = 0; tt < 3; ++tt) {
        const int g = (w + 8 * tt) * 16 + nl;
#pragma unroll
        for (int c = 0; c < 4; ++c) {
            const float* wi = w_ih + (size_t)g * FF + c * 32 + q * 8;
            const float* wh = w_hh + (size_t)g * FF + c * 32 + q * 8;
            short8 a, b;
#pragma unroll
            for (int j = 0; j < 8; ++j) { a[j] = bf_rne(wi[j]); b[j] = bf_rne(wh[j]); }
            wbi[tt][c] = a; wbh[tt][c] = b;
        }
    }
    const int fcol = w * 16 + nl;
    const float bR  = b_ih[fcol] + b_hh[fcol];
    const float bZ  = b_ih[FF + fcol] + b_hh[FF + fcol];
    const float bNi = b_ih[2 * FF + fcol];
    const float bNh = b_hh[2 * FF + fcol];

    if (tid < MB * KK) cix[tid >> 3][tid & 7] = idx[(p0 + (tid >> 3)) * KK + (tid & 7)];

    // ---- producer-side constants: lane owns paths {pb, pb+1} at column fcol
    const int qqF = 2 * (w & 1) + (nl >> 3);
    const int jF  = nl & 7;
    const int cF  = w >> 1;
    const int pb  = 4 * (q & 1) + 2 * (q >> 1);   // q=0->{0,1} 1->{4,5} 2->{2,3} 3->{6,7}
    int sp0, sp1;
    {
        const int pA = pb, pB = pb + 1;
        sp0 = (pA >> 2) + 2 * ((pA & 3) ^ qqF) + 8 * qqF;
        sp1 = (pB >> 2) + 2 * ((pB & 3) ^ qqF) + 8 * qqF;
    }

    // ---- consumer-side constants: A-frag row -> path (dup shuffle rows 8-15)
    const int row = lane & 15;
    const int pr  = (row < 8) ? row : ((row & 4) | ((row & 3) ^ 2));
    const int xslot = pr + 8 * q;                               // identity layout
    const int hslot = (pr >> 2) + 2 * ((pr & 3) ^ q) + 8 * q;   // sigma layout
    const bool rlo = (row < 8);      // dense-x: which ring this lane reads
    const bool lo  = (lane < 32);    // swap/select side

    // ---- h0: f32 master in regs + packed bf16 frags into hhi[0]
    float hm0 = h0[(size_t)(p0 + pb)     * FF + fcol];
    float hm1 = h0[(size_t)(p0 + pb + 1) * FF + fcol];
    {
        const uint32_t hp = cvtpk(hm0, hm1);
        hhi[0][cF][sp0][jF] = (short)hp;
        hhi[0][cF][sp1][jF] = (short)(hp >> 16);
    }

    // ---- x stager mapping: waves 0-3 only; thread = half a frag row
    const bool stg    = tid < 256;
    const int  c_s    = tid >> 6;          // chunk (0..3 for stagers)
    const int  r6     = tid & 63;
    const int  slot_s = r6 >> 1;           // 0..31: path + 8*qq
    const int  half   = r6 & 1;
    const int  path_s = slot_s & 7;
    const int  qq_s   = slot_s >> 3;
    const int  k0s    = c_s * 32 + qq_s * 8 + 4 * half;

    __syncthreads();  // B0: cix ready for stagers

    // prologue staging: x_0,x_1,x_2 -> rings 0,1,2; prefetch x_3,x_4
    float4 xp0, xp1;
    if (stg) {
        const int ch = cix[path_s][0];
        const float* base = feat + (size_t)ch * (TT * FF) + k0s;
        const float4 v0 = *(const float4*)(base);
        const float4 v1 = *(const float4*)(base + FF);
        const float4 v2 = *(const float4*)(base + 2 * FF);
        uint2 a0 = { cvtpk(v0.x, v0.y), cvtpk(v0.z, v0.w) };
        uint2 a1 = { cvtpk(v1.x, v1.y), cvtpk(v1.z, v1.w) };
        uint2 a2 = { cvtpk(v2.x, v2.y), cvtpk(v2.z, v2.w) };
        *(uint2*)&xfr[0][c_s][slot_s][4 * half] = a0;
        *(uint2*)&xfr[1][c_s][slot_s][4 * half] = a1;
        *(uint2*)&xfr[2][c_s][slot_s][4 * half] = a2;
        xp0 = *(const float4*)(base + 3 * FF);
        xp1 = *(const float4*)(base + 4 * FF);
    }
    __syncthreads();  // B1: rings 0-2 + hhi[0] ready

    // prologue: x-gates for step 0 from ring 0 (dup read, regs {0,1} kept)
    float xgE[3][2];
    {
        short8 xa0[4];
#pragma unroll
        for (int c = 0; c < 4; ++c) xa0[c] = *(const short8*)&xfr[0][c][xslot][0];
        f32x4 r = {bR, bR, bR, bR}, z = {bZ, bZ, bZ, bZ}, n = {bNi, bNi, bNi, bNi};
#pragma unroll
        for (int c = 0; c < 4; ++c) {
            r = __builtin_amdgcn_mfma_f32_16x16x32_bf16(xa0[c], wbi[0][c], r, 0, 0, 0);
            z = __builtin_amdgcn_mfma_f32_16x16x32_bf16(xa0[c], wbi[1][c], z, 0, 0, 0);
            n = __builtin_amdgcn_mfma_f32_16x16x32_bf16(xa0[c], wbi[2][c], n, 0, 0, 0);
        }
        xgE[0][0] = r[0]; xgE[0][1] = r[1];
        xgE[1][0] = z[0]; xgE[1][1] = z[1];
        xgE[2][0] = n[0]; xgE[2][1] = n[1];
    }
    __syncthreads();  // B2: ring 0 reads done; macro-0 stagers may overwrite it

    for (int m = 0; m < NMAC; ++m) {
        const int s0 = 2 * m;
        const int r1  = (s0 + 1) & 3, r2  = (s0 + 2) & 3;
        const int wr3 = (s0 + 3) & 3, wr4 = (s0 + 4) & 3;

        // ---- stagers: write x_{s0+3}, x_{s0+4}; prefetch x_{s0+5}, x_{s0+6}
        if (stg) {
            if (s0 + 3 < NSTEP) {
                uint2 pk = { cvtpk(xp0.x, xp0.y), cvtpk(xp0.z, xp0.w) };
                *(uint2*)&xfr[wr3][c_s][slot_s][4 * half] = pk;
            }
            if (s0 + 4 < NSTEP) {
                uint2 pk = { cvtpk(xp1.x, xp1.y), cvtpk(xp1.z, xp1.w) };
                *(uint2*)&xfr[wr4][c_s][slot_s][4 * half] = pk;
            }
            if (s0 + 5 < NSTEP) {
                const int u = s0 + 5;
                xp0 = *(const float4*)(feat + (size_t)cix[path_s][u >> 5] * (TT * FF) + (u & 31) * FF + k0s);
            }
            if (s0 + 6 < NSTEP) {
                const int u = s0 + 6;
                xp1 = *(const float4*)(feat + (size_t)cix[path_s][u >> 5] * (TT * FF) + (u & 31) * FF + k0s);
            }
        }

        // ---- step e = s0: read h frags + dense-x frags (latency overlapped)
        short8 ha[4];
#pragma unroll
        for (int c = 0; c < 4; ++c) ha[c] = *(const short8*)&hhi[0][c][hslot][0];
        const short* xbase = rlo ? &xfr[r1][0][0][0] : &xfr[r2][0][0][0];
        short8 xa[4];
#pragma unroll
        for (int c = 0; c < 4; ++c) xa[c] = *(const short8*)(xbase + c * 32 * 8 + xslot * 8);

        // h-MFMAs chained onto step-e x-gates (r,z) / separate bNh acc (n)
        {
            f32x4 aR = {xgE[0][0], xgE[0][1], 0.f, 0.f};
            f32x4 aZ = {xgE[1][0], xgE[1][1], 0.f, 0.f};
            f32x4 ahN = {bNh, bNh, bNh, bNh};
#pragma unroll
            for (int c = 0; c < 4; ++c) {
                aR  = __builtin_amdgcn_mfma_f32_16x16x32_bf16(ha[c], wbh[0][c], aR, 0, 0, 0);
                aZ  = __builtin_amdgcn_mfma_f32_16x16x32_bf16(ha[c], wbh[1][c], aZ, 0, 0, 0);
                ahN = __builtin_amdgcn_mfma_f32_16x16x32_bf16(ha[c], wbh[2][c], ahN, 0, 0, 0);
            }
#pragma unroll
            for (int j = 0; j < 2; ++j) {
                const float rg  = sigm(aR[j]);
                const float zg  = sigm(aZ[j]);
                const float np_ = xgE[2][j] + rg * ahN[j];
                const float ng  = tanh_fast(np_);
                const float hv  = ng + zg * ((j ? hm1 : hm0) - ng);
                if (j) hm1 = hv; else hm0 = hv;
            }
            const uint32_t hp = cvtpk(hm0, hm1);
            hhi[1][cF][sp0][jF] = (short)hp;
            hhi[1][cF][sp1][jF] = (short)(hp >> 16);
        }

        // ---- dense x-MFMA: rows 0-7 = step s0+1, rows 8-15 = step s0+2
        float xgO[3][2];
        {
            f32x4 dR = {bR, bR, bR, bR}, dZ = {bZ, bZ, bZ, bZ}, dN = {bNi, bNi, bNi, bNi};
#pragma unroll
            for (int c = 0; c < 4; ++c) {
                dR = __builtin_amdgcn_mfma_f32_16x16x32_bf16(xa[c], wbi[0][c], dR, 0, 0, 0);
                dZ = __builtin_amdgcn_mfma_f32_16x16x32_bf16(xa[c], wbi[1][c], dZ, 0, 0, 0);
                dN = __builtin_amdgcn_mfma_f32_16x16x32_bf16(xa[c], wbi[2][c], dN, 0, 0, 0);
            }
            // regs {2,3} cross lane+-32; local regs {0,1} stay.
            // lanes<32: local = step s0+1 (own paths), received = step s0+2.
            {
                const float s2 = __shfl_xor(dR[2], 32);
                const float s3 = __shfl_xor(dR[3], 32);
                xgO[0][0] = lo ? dR[0] : s2;  xgO[0][1] = lo ? dR[1] : s3;
                xgE[0][0] = lo ? s2 : dR[0];  xgE[0][1] = lo ? s3 : dR[1];
            }
            {
                const float s2 = __shfl_xor(dZ[2], 32);
                const float s3 = __shfl_xor(dZ[3], 32);
                xgO[1][0] = lo ? dZ[0] : s2;  xgO[1][1] = lo ? dZ[1] : s3;
                xgE[1][0] = lo ? s2 : dZ[0];  xgE[1][1] = lo ? s3 : dZ[1];
            }
            {
                const float s2 = __shfl_xor(dN[2], 32);
                const float s3 = __shfl_xor(dN[3], 32);
                xgO[2][0] = lo ? dN[0] : s2;  xgO[2][1] = lo ? dN[1] : s3;
                xgE[2][0] = lo ? s2 : dN[0];  xgE[2][1] = lo ? s3 : dN[1];
            }
        }
        __syncthreads();  // mid: hhi[1] exchange ready

        // ---- step o = s0+1
        {
            short8 hb[4];
#pragma unroll
            for (int c = 0; c < 4; ++c) hb[c] = *(const short8*)&hhi[1][c][hslot][0];
            f32x4 aR = {xgO[0][0], xgO[0][1], 0.f, 0.f};
            f32x4 aZ = {xgO[1][0], xgO[1][1], 0.f, 0.f};
            f32x4 ahN = {bNh, bNh, bNh, bNh};
#pragma unroll
            for (int c = 0; c < 4; ++c) {
                aR  = __builtin_amdgcn_mfma_f32_16x16x32_bf16(hb[c], wbh[0][c], aR, 0, 0, 0);
                aZ  = __builtin_amdgcn_mfma_f32_16x16x32_bf16(hb[c], wbh[1][c], aZ, 0, 0, 0);
                ahN = __builtin_amdgcn_mfma_f32_16x16x32_bf16(hb[c], wbh[2][c], ahN, 0, 0, 0);
            }
#pragma unroll
            for (int j = 0; j < 2; ++j) {
                const float rg  = sigm(aR[j]);
                const float zg  = sigm(aZ[j]);
                const float np_ = xgO[2][j] + rg * ahN[j];
                const float ng  = tanh_fast(np_);
                const float hv  = ng + zg * ((j ? hm1 : hm0) - ng);
                if (j) hm1 = hv; else hm0 = hv;
            }
            const uint32_t hp = cvtpk(hm0, hm1);
            hhi[0][cF][sp0][jF] = (short)hp;
            hhi[0][cF][sp1][jF] = (short)(hp >> 16);
        }
        __syncthreads();  // end: hhi[0] exchange + ring writes ready
    }

    // final h straight from registers
    out[(size_t)(p0 + pb)     * FF + fcol] = hm0;
    out[(size_t)(p0 + pb + 1) * FF + fcol] = hm1;
}

extern "C" void kernel_launch(void* const* d_in, const int* in_sizes, int n_in,
                              void* d_out, int out_size, void* d_ws, size_t ws_size,
                              hipStream_t stream) {
    const float* h0   = (const float*)d_in[0];
    const float* feat = (const float*)d_in[1];
    const float* wih  = (const float*)d_in[2];
    const float* whh  = (const float*)d_in[3];
    const float* bih  = (const float*)d_in[4];
    const float* bhh  = (const float*)d_in[5];
    const int*   idx  = (const int*)d_in[6];
    float*       out  = (float*)d_out;

    gru_mfma6<<<dim3(NBLK), dim3(NTHR), 0, stream>>>(
        h0, feat, wih, whh, bih, bhh, idx, out);
}